// Round 9
// baseline (259.468 us; speedup 1.0000x reference)
//
#include <hip/hip_runtime.h>
#include <hip/hip_bf16.h>

// Ensemble MLP: E=8, B=16384, DS=32, DA=8, H=128, din=40 (padded to 48 for K).
// preds[i,j,b,:] = MLP_j(inp[i,b,:]); out0 = mean_i(preds)+states, out1 = var_i(preds, ddof=1)
//
// R9 = R8 with L0/L1 on mfma_f32_32x32x16_bf16 (2x FLOP/instr): MFMA instrs
// per wave-i 56 -> 30 (L0 16->6 incl. skipping the all-zero k=[48,64) step;
// L1 32->16). R8 post-mortem: VALU ~860 instr/wave-i vs ~350 source-level ->
// per-MFMA overhead dominates; halve the instr count. Same LDS traffic, same
// epilogue element count. 32x32 C/D: col=lane&31, row=(reg&3)+8*(reg>>2)+4*(lane>>5).
// Kept from R8: persistent 768 blocks (3/CU), XOR-swizzled unpadded LDS (40960B),
// vectorized staging, bias-as-acc-init, R4-orientation L2 (16x16), deferred b2.

#define NE 8
#define NB 16384
#define DS 32
#define DA 8
#define HH 128
#define DIN 40
#define BT 64            // batch rows per block-tile
#define NSLOT 96         // bt slots (grid = 8*NSLOT = 768)
#define SLOPE 0.01f

using bf16x8 = __attribute__((ext_vector_type(8))) short;
using f32x4  = __attribute__((ext_vector_type(4))) float;
using f32x16 = __attribute__((ext_vector_type(16))) float;

__device__ __forceinline__ unsigned short f2bf(float f) {
    unsigned int u = __float_as_uint(f);
    u += 0x7FFFu + ((u >> 16) & 1u);
    return (unsigned short)(u >> 16);
}

__device__ __forceinline__ float lrelu(float x) { return fmaxf(x, SLOPE * x); }

__device__ __forceinline__ unsigned int pack2bf(float a, float b) {
    union { __hip_bfloat162 h; unsigned int u; } cv;
    cv.h = __float22bfloat162_rn(make_float2(a, b));   // a -> low 16, b -> high 16
    return cv.u;
}

// Swizzled element indices (16B blocks of 8 bf16; block' = block ^ row-bits)
__device__ __forceinline__ int sin_idx(int row, int kb) {          // 64 elts/row
    return row * 64 + ((kb ^ (row & 7)) << 3);
}
__device__ __forceinline__ int sh_idx(int row, int kb) {           // 128 elts/row
    return row * 128 + ((kb ^ (row & 15)) << 3);
}

__global__ __launch_bounds__(256, 3)
void ens_mlp_kernel(const float* __restrict__ states,
                    const float* __restrict__ actions,
                    const float* __restrict__ W0g,
                    const float* __restrict__ b0g,
                    const float* __restrict__ W1g,
                    const float* __restrict__ b1g,
                    const float* __restrict__ W2g,
                    const float* __restrict__ b2g,
                    float* __restrict__ out)
{
    __shared__ __align__(16) unsigned short sIn[BT * 64];     //  8 KB
    __shared__ __align__(16) unsigned short sHa[BT * 128];    // 16 KB
    __shared__ __align__(16) unsigned short sHb[BT * 128];    // 16 KB  -> 40960 total

    const int j    = blockIdx.x & 7;          // j fast-varying
    const int slot = blockIdx.x >> 3;         // 0..95
    const int tid  = threadIdx.x;
    const int wave = tid >> 6;
    const int lane = tid & 63;
    const int h2   = lane >> 5;               // 32x32 frag k-half
    const int m31  = lane & 31;               // 32x32 frag row (batch for B/C, feat for A)
    const int q    = lane >> 4;               // 16x16 (L2) quad
    const int l16  = lane & 15;
    const int fb   = 32 * wave;               // L0/L1: wave owns features fb..fb+31 (A/M dim)
    const int l2m  = 32 * (wave >> 1);        // L2 (16x16, R4 orientation): rows l2m..l2m+31
    const int l2n  = 16 * (wave & 1);         //                             cols l2n..l2n+15

    // zero-fill sIn once (swizzle-invariant); blocks 5..7 stay zero forever
    // (staging only writes blocks 0..4) = K padding cols 40..47 for ks=2.
    {
        uint4 z; z.x = z.y = z.z = z.w = 0u;
        uint4* p = reinterpret_cast<uint4*>(&sIn[tid * 32]);
        p[0] = z; p[1] = z; p[2] = z; p[3] = z;
    }

    const float* W0j = W0g + j * (DIN * HH);
    const float* W1j = W1g + j * (HH * HH);
    const float* W2j = W2g + j * (HH * DS);

    // ---- L0/L1 weight A-fragments (32x32x16): lane holds A[m=m31][k=ks*16+h2*8+t]
    bf16x8 w0f[3];      // 12 VGPRs; K=48 (k in [40,48) zero; [48,64) skipped)
    bf16x8 w1f[8];      // 32 VGPRs; K=128
    bf16x8 w2f[4];      // 16 VGPRs (L2 16x16 B-frags, R4 orientation)
    f32x16 b0v, b1v;    // acc-init biases in 32x32 C-layout
    float b2s;

    #pragma unroll
    for (int ks = 0; ks < 3; ++ks) {
        const int n = fb + m31;
        #pragma unroll
        for (int t = 0; t < 8; ++t) {
            const int k = ks * 16 + h2 * 8 + t;
            w0f[ks][t] = (short)((k < DIN) ? f2bf(W0j[k * HH + n]) : 0);
        }
    }
    #pragma unroll
    for (int ks = 0; ks < 8; ++ks) {
        const int n = fb + m31;
        #pragma unroll
        for (int t = 0; t < 8; ++t) {
            const int k = ks * 16 + h2 * 8 + t;
            w1f[ks][t] = (short)f2bf(W1j[k * HH + n]);
        }
    }
    #pragma unroll
    for (int ks = 0; ks < 4; ++ks) {
        const int n = l2n + l16;
        #pragma unroll
        for (int t = 0; t < 8; ++t) {
            const int k = ks * 32 + q * 8 + t;
            w2f[ks][t] = (short)f2bf(W2j[k * DS + n]);
        }
    }
    #pragma unroll
    for (int r = 0; r < 16; ++r) {
        const int f = fb + (r & 3) + 8 * (r >> 2) + 4 * h2;   // 32x32 C-row mapping
        b0v[r] = b0g[j * HH + f];
        b1v[r] = b1g[j * HH + f];
    }
    b2s = b2g[j * DS + l2n + l16];

    const f32x4 z4 = {0.f, 0.f, 0.f, 0.f};

    // staging geometry (constant across i and bt)
    const int srow = tid >> 2;        // states: row 0..63
    const int scb  = tid & 3;         // states: k-block 0..3
    const int soff = srow * DS + scb * 8;          // f32 offset within slice
    unsigned short* const sdst = &sIn[sin_idx(srow, scb)];
    unsigned short* const adst = &sIn[sin_idx(lane, 4)];   // wave 0 only

    for (int bt = slot; bt < NB / BT; bt += NSLOT) {
        const int b0 = bt * BT;

        // ---- stage inp[0] (vectorized) ----
        {
            const float4* sp = reinterpret_cast<const float4*>(
                states + (size_t)b0 * DS + soff);
            const float4 f0 = sp[0], f1 = sp[1];
            uint4 pk;
            pk.x = pack2bf(f0.x, f0.y); pk.y = pack2bf(f0.z, f0.w);
            pk.z = pack2bf(f1.x, f1.y); pk.w = pack2bf(f1.z, f1.w);
            *reinterpret_cast<uint4*>(sdst) = pk;
            if (tid < BT) {
                const float4* ap = reinterpret_cast<const float4*>(
                    actions + ((size_t)b0 + lane) * DA);
                const float4 a0 = ap[0], a1 = ap[1];
                uint4 apk;
                apk.x = pack2bf(a0.x, a0.y); apk.y = pack2bf(a0.z, a0.w);
                apk.z = pack2bf(a1.x, a1.y); apk.w = pack2bf(a1.z, a1.w);
                *reinterpret_cast<uint4*>(adst) = apk;
            }
        }
        __syncthreads();

        float sa[2][4], sq[2][4];
        #pragma unroll
        for (int mt = 0; mt < 2; ++mt)
          #pragma unroll
          for (int r = 0; r < 4; ++r) { sa[mt][r] = 0.f; sq[mt][r] = 0.f; }

        for (int i = 0; i < NE; ++i) {
            // ---- Layer 0: h0 = lrelu(W0^T inp + b0); 32x32x16, K=48 ----
            #pragma unroll
            for (int nh = 0; nh < 2; ++nh) {          // batch halves of 32
                f32x16 acc = b0v;
                const int row = nh * 32 + m31;
                #pragma unroll
                for (int ks = 0; ks < 3; ++ks) {
                    const bf16x8 bb = *(const bf16x8*)(&sIn[sin_idx(row, ks * 2 + h2)]);
                    acc = __builtin_amdgcn_mfma_f32_32x32x16_bf16(w0f[ks], bb, acc, 0, 0, 0);
                }
                // lane: batch col m31, feats fb + 8g + 4h2 + {0..3} from regs 4g..4g+3
                #pragma unroll
                for (int g = 0; g < 4; ++g) {
                    const int idx = sh_idx(row, (fb >> 3) + g) + h2 * 4;
                    const float v0 = lrelu(acc[4 * g + 0]);
                    const float v1 = lrelu(acc[4 * g + 1]);
                    const float v2 = lrelu(acc[4 * g + 2]);
                    const float v3 = lrelu(acc[4 * g + 3]);
                    uint2 pk; pk.x = pack2bf(v0, v1); pk.y = pack2bf(v2, v3);
                    *reinterpret_cast<uint2*>(&sHa[idx]) = pk;
                }
            }
            __syncthreads();   // B2: h0 ready; sIn reads drained

            // ---- stage inp[i+1] (overlaps L1; writes blocks 0..4 only) ----
            if (i < NE - 1) {
                const float4* sp = reinterpret_cast<const float4*>(
                    states + ((size_t)(i + 1) * NB + b0) * DS + soff);
                const float4 f0 = sp[0], f1 = sp[1];
                uint4 pk;
                pk.x = pack2bf(f0.x, f0.y); pk.y = pack2bf(f0.z, f0.w);
                pk.z = pack2bf(f1.x, f1.y); pk.w = pack2bf(f1.z, f1.w);
                *reinterpret_cast<uint4*>(sdst) = pk;
                if (tid < BT) {
                    const float4* ap = reinterpret_cast<const float4*>(
                        actions + ((size_t)(i + 1) * NB + b0 + lane) * DA);
                    const float4 a0 = ap[0], a1 = ap[1];
                    uint4 apk;
                    apk.x = pack2bf(a0.x, a0.y); apk.y = pack2bf(a0.z, a0.w);
                    apk.z = pack2bf(a1.x, a1.y); apk.w = pack2bf(a1.z, a1.w);
                    *reinterpret_cast<uint4*>(adst) = apk;
                }
            }

            // ---- Layer 1: h1 = lrelu(W1^T h0 + b1); 32x32x16, K=128 ----
            #pragma unroll
            for (int nh = 0; nh < 2; ++nh) {
                f32x16 acc = b1v;
                const int row = nh * 32 + m31;
                #pragma unroll
                for (int ks = 0; ks < 8; ++ks) {
                    const bf16x8 bb = *(const bf16x8*)(&sHa[sh_idx(row, ks * 2 + h2)]);
                    acc = __builtin_amdgcn_mfma_f32_32x32x16_bf16(w1f[ks], bb, acc, 0, 0, 0);
                }
                #pragma unroll
                for (int g = 0; g < 4; ++g) {
                    const int idx = sh_idx(row, (fb >> 3) + g) + h2 * 4;
                    const float v0 = lrelu(acc[4 * g + 0]);
                    const float v1 = lrelu(acc[4 * g + 1]);
                    const float v2 = lrelu(acc[4 * g + 2]);
                    const float v3 = lrelu(acc[4 * g + 3]);
                    uint2 pk; pk.x = pack2bf(v0, v1); pk.y = pack2bf(v2, v3);
                    *reinterpret_cast<uint2*>(&sHb[idx]) = pk;
                }
            }
            __syncthreads();   // B3: h1 + sIn(i+1) ready

            // ---- Layer 2 (16x16x32, R4 orientation): A=h1 (m=batch), B=W2 ----
            {
                f32x4 acc2[2];
                acc2[0] = z4; acc2[1] = z4;
                #pragma unroll
                for (int ks = 0; ks < 4; ++ks) {
                    #pragma unroll
                    for (int mt = 0; mt < 2; ++mt) {
                        const int row = l2m + 16 * mt + l16;
                        const bf16x8 a2 = *(const bf16x8*)(&sHb[sh_idx(row, ks * 4 + q)]);
                        acc2[mt] = __builtin_amdgcn_mfma_f32_16x16x32_bf16(
                            a2, w2f[ks], acc2[mt], 0, 0, 0);
                    }
                }
                #pragma unroll
                for (int mt = 0; mt < 2; ++mt)
                  #pragma unroll
                  for (int r = 0; r < 4; ++r) {
                    const float a = acc2[mt][r];      // b2 deferred
                    sa[mt][r] += a;
                    sq[mt][r] = fmaf(a, a, sq[mt][r]);
                  }
            }
        }

        // ---- Epilogue for this bt: sum = sa + 8b; sum(p^2) = sq + 2b*sa + 8b^2
        #pragma unroll
        for (int mt = 0; mt < 2; ++mt)
          #pragma unroll
          for (int r = 0; r < 4; ++r) {
            const int row = l2m + 16 * mt + q * 4 + r;   // batch row (16x16 C: row=quad*4+r)
            const int col = l2n + l16;                   // feature
            const size_t o = ((size_t)j * NB + b0 + row) * DS + col;
            const float b  = b2s;
            const float s  = sa[mt][r] + 8.f * b;
            const float s2 = sq[mt][r] + 2.f * b * sa[mt][r] + 8.f * b * b;
            out[o] = s * 0.125f + states[o];
            out[(size_t)NE * NB * DS + o] = (s2 - s * s * 0.125f) * (1.0f / 7.0f);
          }
    }
}

extern "C" void kernel_launch(void* const* d_in, const int* in_sizes, int n_in,
                              void* d_out, int out_size, void* d_ws, size_t ws_size,
                              hipStream_t stream) {
    (void)in_sizes; (void)n_in; (void)d_ws; (void)ws_size; (void)out_size;
    const float* states  = (const float*)d_in[0];
    const float* actions = (const float*)d_in[1];
    const float* W0 = (const float*)d_in[2];
    const float* b0 = (const float*)d_in[3];
    const float* W1 = (const float*)d_in[4];
    const float* b1 = (const float*)d_in[5];
    const float* W2 = (const float*)d_in[6];
    const float* b2 = (const float*)d_in[7];
    float* out = (float*)d_out;
    dim3 grid(8 * NSLOT);   // 768 persistent blocks = 3/CU, one generation
    ens_mlp_kernel<<<grid, dim3(256), 0, stream>>>(states, actions, W0, b0, W1, b1, W2, b2, out);
}